// Round 9
// baseline (631.160 us; speedup 1.0000x reference)
//
#include <hip/hip_runtime.h>
#include <cstddef>

// Shapes (hard-coded): B=2, L=4096 (64x64), C=256, H=8, D=32, K=9, scale=8,
// layers: self,cross,self,cross. X rows: 0..8191 feat0 (b0,b1), 8192..16383 feat1.

#define NROWS 16384

typedef unsigned short ushort_t;
typedef __attribute__((ext_vector_type(8))) short short8;
typedef __attribute__((ext_vector_type(4))) float f32x4;
typedef __attribute__((ext_vector_type(4))) unsigned short ushort4_t;
typedef __attribute__((ext_vector_type(8))) unsigned short ushort8_t;

__device__ __forceinline__ float b2f(unsigned short u) {
    union { unsigned int i; float f; } v; v.i = (unsigned int)u << 16; return v.f;
}
__device__ __forceinline__ unsigned short f2b(float x) {
    union { float f; unsigned int i; } v; v.f = x;
    unsigned int r = v.i + 0x7fffu + ((v.i >> 16) & 1u);   // RNE
    return (unsigned short)(r >> 16);
}
// elu(x)+1: for x<=0, elu = exp(x)-1, so elu+1 = exp(x) exactly.
__device__ __forceinline__ float elu1(float x) {
    return x > 0.f ? x + 1.f : __expf(x);
}

#define ASYNC_COPY16(gptr, lptr) \
    __builtin_amdgcn_global_load_lds((const __attribute__((address_space(1))) void*)(gptr), \
                                     (__attribute__((address_space(3))) void*)(lptr), 16, 0, 0)

// ---------------------------------------------------------------------------
// bf16 MFMA GEMM: C[M,N] = A[M,K] @ W[K,N], W pre-transposed as Wt[N][K].
// 128x128 tile, BK=64 (two 32-col LDS panels). Used for the QKV projection.
// Side duty: blocks with blockIdx.y==0 zero the KVb/KSb accumulators (132+4 KB)
// so the later kv_reduce atomics need no separate memset dispatch.
// ---------------------------------------------------------------------------
__global__ __launch_bounds__(256) void gemm_bf16_kernel(
    const ushort_t* __restrict__ A0, int lda0,
    const ushort_t* __restrict__ Wt, int ldw,
    ushort_t* __restrict__ C, int ldc, int Kd,
    float* __restrict__ zbuf, int znf4)   // zero zbuf[0..znf4*4) floats
{
    __shared__ ushort_t As[128 * 64];   // 16 KB
    __shared__ ushort_t Bs[128 * 64];   // 16 KB

    int tid = threadIdx.x;
    int m0 = blockIdx.y * 128;
    int n0 = blockIdx.x * 128;
    int lane = tid & 63, w = tid >> 6;
    int wrow = w >> 1, wcol = w & 1;
    int quad = lane >> 4, l16 = lane & 15;

    if (zbuf && blockIdx.y == 0) {
        int nblk = gridDim.x;
        for (int i = blockIdx.x * 256 + tid; i < znf4; i += nblk * 256)
            *(float4*)&zbuf[(size_t)i * 4] = (float4){0.f, 0.f, 0.f, 0.f};
    }

    f32x4 acc[4][4];
    #pragma unroll
    for (int i = 0; i < 4; i++)
        #pragma unroll
        for (int j = 0; j < 4; j++) acc[i][j] = (f32x4){0.f, 0.f, 0.f, 0.f};

    for (int kb = 0; kb < Kd; kb += 64) {
        #pragma unroll
        for (int q = 0; q < 4; q++) {
            int s = q * 256 + tid;
            int kk = s >> 9, p = s & 511;
            int row = p >> 2, c4 = p & 3;
            ASYNC_COPY16(A0 + (size_t)(m0 + row) * lda0 + kb + kk * 32 + c4 * 8,
                         (char*)As + s * 16);
        }
        #pragma unroll
        for (int q = 0; q < 4; q++) {
            int s = q * 256 + tid;
            int kk = s >> 9, p = s & 511;
            int row = p >> 2, c4 = p & 3;
            ASYNC_COPY16(Wt + (size_t)(n0 + row) * ldw + kb + kk * 32 + c4 * 8,
                         (char*)Bs + s * 16);
        }
        __syncthreads();

        #pragma unroll
        for (int kk = 0; kk < 2; kk++) {
            short8 af[4], bf[4];
            #pragma unroll
            for (int mt = 0; mt < 4; mt++)
                af[mt] = *(const short8*)&As[kk * 4096 + (wrow * 64 + mt * 16 + l16) * 32 + quad * 8];
            #pragma unroll
            for (int nt = 0; nt < 4; nt++)
                bf[nt] = *(const short8*)&Bs[kk * 4096 + (wcol * 64 + nt * 16 + l16) * 32 + quad * 8];
            #pragma unroll
            for (int mt = 0; mt < 4; mt++)
                #pragma unroll
                for (int nt = 0; nt < 4; nt++)
                    acc[mt][nt] = __builtin_amdgcn_mfma_f32_16x16x32_bf16(
                        af[mt], bf[nt], acc[mt][nt], 0, 0, 0);
        }
        __syncthreads();
    }

    #pragma unroll
    for (int mt = 0; mt < 4; mt++) {
        int row = m0 + wrow * 64 + mt * 16 + quad * 4;
        #pragma unroll
        for (int nt = 0; nt < 4; nt++) {
            int col = n0 + wcol * 64 + nt * 16 + l16;
            #pragma unroll
            for (int r = 0; r < 4; r++)
                C[(size_t)(row + r) * ldc + col] = f2b(acc[mt][nt][r]);
        }
    }
}

// ---------------------------------------------------------------------------
// GEMM + fused LayerNorm (the Wm -> ln1 path). 32 rows x 256 cols per block,
// BK=64 two-panel LDS layout. OutBf = bf16(LN(A@Wt)).
// ---------------------------------------------------------------------------
__global__ __launch_bounds__(256) void gemm_ln_kernel(
    const ushort_t* __restrict__ A, int lda,
    const ushort_t* __restrict__ Wt, int ldw, int Kd,
    const float* __restrict__ g, const float* __restrict__ bp,
    ushort_t* __restrict__ OutBf)
{
    __shared__ ushort_t As[32 * 64];    // 4 KB, panels of 32x32
    __shared__ ushort_t Bs[256 * 64];   // 32 KB, panels of 256x32
    __shared__ float rsum[4][32];
    __shared__ float rsq[4][32];

    int tid = threadIdx.x;
    int m0 = blockIdx.x * 32;
    int lane = tid & 63, w = tid >> 6;
    int quad = lane >> 4, l16 = lane & 15;

    f32x4 acc[2][4];
    #pragma unroll
    for (int i = 0; i < 2; i++)
        #pragma unroll
        for (int j = 0; j < 4; j++) acc[i][j] = (f32x4){0.f, 0.f, 0.f, 0.f};

    for (int kb = 0; kb < Kd; kb += 64) {
        {
            int s = tid;
            int kk = s >> 7, p = s & 127;
            int row = p >> 2, c4 = p & 3;
            ASYNC_COPY16(A + (size_t)(m0 + row) * lda + kb + kk * 32 + c4 * 8,
                         (char*)As + s * 16);
        }
        #pragma unroll
        for (int q = 0; q < 8; q++) {
            int s = q * 256 + tid;
            int kk = s >> 10, p = s & 1023;
            int row = p >> 2, c4 = p & 3;
            ASYNC_COPY16(Wt + (size_t)(row) * ldw + kb + kk * 32 + c4 * 8,
                         (char*)Bs + s * 16);
        }
        __syncthreads();

        #pragma unroll
        for (int kk = 0; kk < 2; kk++) {
            short8 af[2], bf[4];
            #pragma unroll
            for (int mt = 0; mt < 2; mt++)
                af[mt] = *(const short8*)&As[kk * 1024 + (mt * 16 + l16) * 32 + quad * 8];
            #pragma unroll
            for (int nt = 0; nt < 4; nt++)
                bf[nt] = *(const short8*)&Bs[kk * 8192 + (w * 64 + nt * 16 + l16) * 32 + quad * 8];
            #pragma unroll
            for (int mt = 0; mt < 2; mt++)
                #pragma unroll
                for (int nt = 0; nt < 4; nt++)
                    acc[mt][nt] = __builtin_amdgcn_mfma_f32_16x16x32_bf16(
                        af[mt], bf[nt], acc[mt][nt], 0, 0, 0);
        }
        __syncthreads();
    }

    #pragma unroll
    for (int mt = 0; mt < 2; mt++)
        #pragma unroll
        for (int r = 0; r < 4; r++) {
            float s = 0.f, q = 0.f;
            #pragma unroll
            for (int nt = 0; nt < 4; nt++) {
                float v = acc[mt][nt][r];
                s += v; q += v * v;
            }
            #pragma unroll
            for (int off = 1; off < 16; off <<= 1) {
                s += __shfl_xor(s, off, 64);
                q += __shfl_xor(q, off, 64);
            }
            if (l16 == 0) {
                rsum[w][mt * 16 + quad * 4 + r] = s;
                rsq[w][mt * 16 + quad * 4 + r]  = q;
            }
        }
    __syncthreads();

    #pragma unroll
    for (int mt = 0; mt < 2; mt++) {
        #pragma unroll
        for (int r = 0; r < 4; r++) {
            int rl = mt * 16 + quad * 4 + r;
            float s = rsum[0][rl] + rsum[1][rl] + rsum[2][rl] + rsum[3][rl];
            float q = rsq[0][rl] + rsq[1][rl] + rsq[2][rl] + rsq[3][rl];
            float m = s * (1.f / 256.f);
            float var = q * (1.f / 256.f) - m * m;
            float rs = rsqrtf(var + 1e-5f);
            size_t row = (size_t)(m0 + rl);
            #pragma unroll
            for (int nt = 0; nt < 4; nt++) {
                int col = w * 64 + nt * 16 + l16;
                float y = (acc[mt][nt][r] - m) * rs * g[col] + bp[col];
                OutBf[row * 256 + col] = f2b(y);
            }
        }
    }
}

// ---------------------------------------------------------------------------
// Fused MLP tail: per 32-row block,
//   stage1: T = tanh([Xb|L1] @ W1t)   (32x512, kept in XOR-swizzled LDS)
//   stage2: M2 = T @ W2t ; xn = Xin + LN(M2); Xout = xn; XbfOut = bf16(xn)
// ---------------------------------------------------------------------------
__global__ __launch_bounds__(256) void mlp_fused_kernel(
    const ushort_t* __restrict__ Xb, const ushort_t* __restrict__ L1,
    const ushort_t* __restrict__ W1t, const ushort_t* __restrict__ W2t,
    const float* __restrict__ g, const float* __restrict__ bp,
    ushort_t* __restrict__ XbfOut, const float* __restrict__ Xin,
    float* __restrict__ Xout)
{
    __shared__ ushort_t Tt[32 * 512];   // 32 KB, XOR-swizzled by (col>>3)^(row&7)
    __shared__ char buf[20480];         // stage1: As 4K + Bs 16K ; stage2: Bs2 16K ; epi: stats

    ushort_t* As  = (ushort_t*)buf;
    ushort_t* Bs  = (ushort_t*)(buf + 4096);
    ushort_t* Bs2 = (ushort_t*)buf;
    float* rsum = (float*)buf;          // [4][32] (dead staging region by epilogue)
    float* rsq  = (float*)(buf + 512);

    int tid = threadIdx.x;
    int m0 = blockIdx.x * 32;
    int lane = tid & 63, w = tid >> 6;
    int quad = lane >> 4, l16 = lane & 15;

    // ---------- stage 1: 4 N-passes of 128 cols ----------
    for (int np = 0; np < 4; np++) {
        f32x4 acc[2][2];
        #pragma unroll
        for (int i = 0; i < 2; i++)
            #pragma unroll
            for (int j = 0; j < 2; j++) acc[i][j] = (f32x4){0.f, 0.f, 0.f, 0.f};

        for (int kb = 0; kb < 512; kb += 64) {
            const ushort_t* Ab = (kb < 256) ? Xb : L1;
            int kc = (kb < 256) ? kb : kb - 256;
            {
                int s = tid;
                int kk = s >> 7, p = s & 127;
                ASYNC_COPY16(Ab + (size_t)(m0 + (p >> 2)) * 256 + kc + kk * 32 + (p & 3) * 8,
                             (char*)As + s * 16);
            }
            #pragma unroll
            for (int q = 0; q < 4; q++) {
                int s = q * 256 + tid;
                int kk = s >> 9, p = s & 511;
                ASYNC_COPY16(W1t + (size_t)(np * 128 + (p >> 2)) * 512 + kb + kk * 32 + (p & 3) * 8,
                             (char*)Bs + s * 16);
            }
            __syncthreads();

            #pragma unroll
            for (int kk = 0; kk < 2; kk++) {
                short8 af[2], bfr[2];
                #pragma unroll
                for (int mt = 0; mt < 2; mt++)
                    af[mt] = *(const short8*)&As[kk * 1024 + (mt * 16 + l16) * 32 + quad * 8];
                #pragma unroll
                for (int nt = 0; nt < 2; nt++)
                    bfr[nt] = *(const short8*)&Bs[kk * 4096 + (w * 32 + nt * 16 + l16) * 32 + quad * 8];
                #pragma unroll
                for (int mt = 0; mt < 2; mt++)
                    #pragma unroll
                    for (int nt = 0; nt < 2; nt++)
                        acc[mt][nt] = __builtin_amdgcn_mfma_f32_16x16x32_bf16(
                            af[mt], bfr[nt], acc[mt][nt], 0, 0, 0);
            }
            __syncthreads();
        }

        // write tanh(acc) into Tt (swizzled)
        #pragma unroll
        for (int mt = 0; mt < 2; mt++)
            #pragma unroll
            for (int nt = 0; nt < 2; nt++)
                #pragma unroll
                for (int r = 0; r < 4; r++) {
                    int trow = mt * 16 + quad * 4 + r;
                    int col = np * 128 + w * 32 + nt * 16 + l16;
                    int c8s = (col >> 3) ^ (trow & 7);
                    Tt[trow * 512 + c8s * 8 + (col & 7)] = f2b(tanhf(acc[mt][nt][r]));
                }
    }

    // ---------- stage 2: 2 N-passes of 128 cols, acc kept across passes ----------
    f32x4 acc2[2][2][2];
    #pragma unroll
    for (int a = 0; a < 2; a++)
        #pragma unroll
        for (int i = 0; i < 2; i++)
            #pragma unroll
            for (int j = 0; j < 2; j++) acc2[a][i][j] = (f32x4){0.f, 0.f, 0.f, 0.f};

    for (int pass = 0; pass < 2; pass++) {
        for (int kb = 0; kb < 512; kb += 64) {
            #pragma unroll
            for (int q = 0; q < 4; q++) {
                int s = q * 256 + tid;
                int kk = s >> 9, p = s & 511;
                ASYNC_COPY16(W2t + (size_t)(pass * 128 + (p >> 2)) * 512 + kb + kk * 32 + (p & 3) * 8,
                             (char*)Bs2 + s * 16);
            }
            __syncthreads();

            #pragma unroll
            for (int kk = 0; kk < 2; kk++) {
                short8 af[2], bfr[2];
                #pragma unroll
                for (int mt = 0; mt < 2; mt++) {
                    int row = mt * 16 + l16;
                    int blk = ((kb >> 3) + kk * 4 + quad) ^ (row & 7);
                    af[mt] = *(const short8*)&Tt[row * 512 + blk * 8];
                }
                #pragma unroll
                for (int nt = 0; nt < 2; nt++)
                    bfr[nt] = *(const short8*)&Bs2[kk * 4096 + (w * 32 + nt * 16 + l16) * 32 + quad * 8];
                #pragma unroll
                for (int mt = 0; mt < 2; mt++)
                    #pragma unroll
                    for (int nt = 0; nt < 2; nt++)
                        acc2[pass][mt][nt] = __builtin_amdgcn_mfma_f32_16x16x32_bf16(
                            af[mt], bfr[nt], acc2[pass][mt][nt], 0, 0, 0);
            }
            __syncthreads();
        }
    }

    // ---------- epilogue: LN + residual ----------
    #pragma unroll
    for (int mt = 0; mt < 2; mt++)
        #pragma unroll
        for (int r = 0; r < 4; r++) {
            float s = 0.f, q = 0.f;
            #pragma unroll
            for (int pass = 0; pass < 2; pass++)
                #pragma unroll
                for (int nt = 0; nt < 2; nt++) {
                    float v = acc2[pass][mt][nt][r];
                    s += v; q += v * v;
                }
            #pragma unroll
            for (int off = 1; off < 16; off <<= 1) {
                s += __shfl_xor(s, off, 64);
                q += __shfl_xor(q, off, 64);
            }
            if (l16 == 0) {
                rsum[w * 32 + mt * 16 + quad * 4 + r] = s;
                rsq[w * 32 + mt * 16 + quad * 4 + r]  = q;
            }
        }
    __syncthreads();

    #pragma unroll
    for (int mt = 0; mt < 2; mt++) {
        #pragma unroll
        for (int r = 0; r < 4; r++) {
            int rl = mt * 16 + quad * 4 + r;
            float s = rsum[rl] + rsum[32 + rl] + rsum[64 + rl] + rsum[96 + rl];
            float q = rsq[rl] + rsq[32 + rl] + rsq[64 + rl] + rsq[96 + rl];
            float m = s * (1.f / 256.f);
            float var = q * (1.f / 256.f) - m * m;
            float rs = rsqrtf(var + 1e-5f);
            size_t row = (size_t)(m0 + rl);
            #pragma unroll
            for (int pass = 0; pass < 2; pass++)
                #pragma unroll
                for (int nt = 0; nt < 2; nt++) {
                    int col = pass * 128 + w * 32 + nt * 16 + l16;
                    float y = (acc2[pass][mt][nt][r] - m) * rs * g[col] + bp[col];
                    float xn = Xin[row * 256 + col] + y;
                    Xout[row * 256 + col] = xn;
                    XbfOut[row * 256 + col] = f2b(xn);
                }
        }
    }
}

// ---------------------------------------------------------------------------
// Weight prep: fp32 [K][N] -> bf16 transposed [N][K]; q/k/v fused into [768][256].
// ---------------------------------------------------------------------------
__global__ __launch_bounds__(256) void wprep_kernel(
    const float* __restrict__ Wq, const float* __restrict__ Wk,
    const float* __restrict__ Wv, const float* __restrict__ Wm,
    const float* __restrict__ W1, const float* __restrict__ W2,
    ushort_t* __restrict__ Wqkvt, ushort_t* __restrict__ Wmt,
    ushort_t* __restrict__ W1t, ushort_t* __restrict__ W2t)
{
    int t = blockIdx.x;
    int layer = t / 640, r = t % 640;
    const float* src; ushort_t* dst;
    int ldsrc, lddst, tn, tk;
    if (r < 192) {
        int grp = r / 64, rr = r % 64; tn = rr / 8; tk = rr % 8;
        src = (grp == 0 ? Wq : grp == 1 ? Wk : Wv) + (size_t)layer * 65536;
        ldsrc = 256;
        dst = Wqkvt + (size_t)layer * 196608 + (size_t)grp * 65536;
        lddst = 256;
    } else if (r < 256) {
        int rr = r - 192; tn = rr / 8; tk = rr % 8;
        src = Wm + (size_t)layer * 65536; ldsrc = 256;
        dst = Wmt + (size_t)layer * 65536; lddst = 256;
    } else if (r < 512) {
        int rr = r - 256; tn = rr / 16; tk = rr % 16;
        src = W1 + (size_t)layer * 262144; ldsrc = 512;
        dst = W1t + (size_t)layer * 262144; lddst = 512;
    } else {
        int rr = r - 512; tn = rr / 16; tk = rr % 16;
        src = W2 + (size_t)layer * 131072; ldsrc = 256;
        dst = W2t + (size_t)layer * 131072; lddst = 512;
    }
    int n0 = tn * 32, k0 = tk * 32;
    __shared__ float tileS[32][33];
    int j = threadIdx.x & 31, i0 = threadIdx.x >> 5;
    #pragma unroll
    for (int p = 0; p < 4; p++) {
        int i = i0 + p * 8;
        tileS[i][j] = src[(size_t)(k0 + i) * ldsrc + n0 + j];
    }
    __syncthreads();
    #pragma unroll
    for (int p = 0; p < 4; p++) {
        int i = i0 + p * 8;
        dst[(size_t)(n0 + i) * lddst + k0 + j] = f2b(tileS[j][i]);
    }
}

// init: X fp32 master + Xbf bf16 mirror from feat0/feat1
__global__ __launch_bounds__(256) void init_kernel(
    const float* __restrict__ f0, const float* __restrict__ f1,
    float* __restrict__ X, ushort_t* __restrict__ Xbf)
{
    int idx = blockIdx.x * 256 + threadIdx.x;      // per float4; 1,048,576 total
    size_t e = (size_t)idx * 4;
    float4 v = (e < 2097152) ? *(const float4*)&f0[e] : *(const float4*)&f1[e - 2097152];
    *(float4*)&X[e] = v;
    ushort4_t u = { f2b(v.x), f2b(v.y), f2b(v.z), f2b(v.w) };
    *(ushort4_t*)&Xbf[e] = u;
}

// ---------------------------------------------------------------------------
// Self-attention KV[g,32,32] + Ksum[g,32] over S=4096, bf16 in (QKV fused, ld=768).
// ---------------------------------------------------------------------------
__global__ __launch_bounds__(256) void kv_reduce_kernel(
    const ushort_t* __restrict__ QKV,
    const int* __restrict__ mask0, const int* __restrict__ mask1,
    float* __restrict__ KV, float* __restrict__ Ksum)
{
    int g = blockIdx.y;
    int t = g >> 4, b = (g >> 3) & 1, h = g & 7;
    const int* mask = t ? mask1 : mask0;
    int rowbase = t * 8192 + b * 4096;
    int s_begin = blockIdx.x * 256;

    __shared__ float sK[32][32];
    __shared__ float sV[32][32];

    int tid = threadIdx.x;
    int e  = tid & 31;
    int dq = tid >> 5;              // 0..7 ; this thread owns d = dq*4..dq*4+3

    float acc[4] = {0.f, 0.f, 0.f, 0.f};
    float ks[4]  = {0.f, 0.f, 0.f, 0.f};

    for (int s0 = s_begin; s0 < s_begin + 256; s0 += 32) {
        #pragma unroll
        for (int q = 0; q < 2; q++) {
            int idx = tid + q * 256;
            int rl = idx >> 4;
            int part = idx & 15;
            int s = s0 + rl;
            size_t row = (size_t)(rowbase + s);
            float m = mask[b * 4096 + s] ? 1.f : 0.f;
            if (part < 8) {
                ushort4_t u = *(const ushort4_t*)&QKV[row * 768 + 256 + h * 32 + part * 4];
                float4 f = { elu1(b2f(u.x)) * m, elu1(b2f(u.y)) * m,
                             elu1(b2f(u.z)) * m, elu1(b2f(u.w)) * m };
                *(float4*)&sK[rl][part * 4] = f;
            } else {
                ushort4_t u = *(const ushort4_t*)&QKV[row * 768 + 512 + h * 32 + (part - 8) * 4];
                float4 f = { b2f(u.x) * m, b2f(u.y) * m, b2f(u.z) * m, b2f(u.w) * m };
                *(float4*)&sV[rl][(part - 8) * 4] = f;
            }
        }
        __syncthreads();

        #pragma unroll
        for (int s = 0; s < 32; s++) {
            float4 kq = *(const float4*)&sK[s][dq * 4];
            float vv = sV[s][e];
            acc[0] += kq.x * vv;
            acc[1] += kq.y * vv;
            acc[2] += kq.z * vv;
            acc[3] += kq.w * vv;
            ks[0] += kq.x; ks[1] += kq.y; ks[2] += kq.z; ks[3] += kq.w;
        }
        __syncthreads();
    }

    #pragma unroll
    for (int j = 0; j < 4; j++)
        atomicAdd(&KV[(size_t)g * 1024 + (dq * 4 + j) * 32 + e], acc[j]);
    if (e == 0) {
        #pragma unroll
        for (int j = 0; j < 4; j++)
            atomicAdd(&Ksum[g * 32 + dq * 4 + j], ks[j]);
    }
}

__global__ __launch_bounds__(256) void attn_apply_kernel(
    const ushort_t* __restrict__ QKV, const float* __restrict__ KV,
    const float* __restrict__ Ksum, ushort_t* __restrict__ MSG)
{
    int row = blockIdx.x;
    int t = row >> 13, bb = (row >> 12) & 1;
    int gb = (t * 2 + bb) * 8;
    int c = threadIdx.x, h = c >> 5, e = c & 31;
    int g = gb + h;

    __shared__ float sQ[256];
    float qf = elu1(b2f(QKV[(size_t)row * 768 + c]));
    sQ[c] = qf;
    __syncthreads();

    float p = qf * Ksum[g * 32 + e];
    #pragma unroll
    for (int off = 16; off; off >>= 1) p += __shfl_xor(p, off, 32);
    float Z = 1.f / (p + 1e-6f);

    float acc = 0.f;
    #pragma unroll
    for (int d = 0; d < 32; d++)
        acc += sQ[h * 32 + d] * KV[(size_t)g * 1024 + d * 32 + e];

    MSG[(size_t)row * 256 + c] = f2b(acc * Z);
}

// ---------------------------------------------------------------------------
// Gram table: 12-float stride (10 used + 2 pad for 16B-aligned loads).
// G order: 00,01,02,03,11,12,13,22,23,33.
// ---------------------------------------------------------------------------
__global__ __launch_bounds__(256) void gram_kernel(
    const ushort_t* __restrict__ Xbf, float* __restrict__ Gm)
{
    int a = blockIdx.x * 4 + (threadIdx.x >> 6);
    int lane = threadIdx.x & 63;
    int img = a / 4225;
    int rr = a - img * 4225;
    int ay = rr / 65, ax = rr - ay * 65;
    int xa = ax > 0 ? ax - 1 : 0;
    int xb = ax < 64 ? ax : 63;
    if (ax == 0) xb = 0;
    int ya = ay > 0 ? ay - 1 : 0;
    int yb = ay < 64 ? ay : 63;
    if (ay == 0) yb = 0;

    size_t rbase = (size_t)img * 4096;
    size_t r0 = (rbase + ya * 64 + xa) * 256;
    size_t r1 = (rbase + ya * 64 + xb) * 256;
    size_t r2 = (rbase + yb * 64 + xa) * 256;
    size_t r3 = (rbase + yb * 64 + xb) * 256;

    int c4 = lane * 4;
    ushort4_t u0 = *(const ushort4_t*)&Xbf[r0 + c4];
    ushort4_t u1 = *(const ushort4_t*)&Xbf[r1 + c4];
    ushort4_t u2 = *(const ushort4_t*)&Xbf[r2 + c4];
    ushort4_t u3 = *(const ushort4_t*)&Xbf[r3 + c4];

    float p[10] = {0,0,0,0,0,0,0,0,0,0};
    #pragma unroll
    for (int j = 0; j < 4; j++) {
        float f0 = b2f(u0[j]), f1 = b2f(u1[j]), f2 = b2f(u2[j]), f3 = b2f(u3[j]);
        p[0] += f0 * f0; p[1] += f0 * f1; p[2] += f0 * f2; p[3] += f0 * f3;
        p[4] += f1 * f1; p[5] += f1 * f2; p[6] += f1 * f3;
        p[7] += f2 * f2; p[8] += f2 * f3; p[9] += f3 * f3;
    }
    #pragma unroll
    for (int k = 0; k < 10; k++)
        #pragma unroll
        for (int off = 32; off; off >>= 1) p[k] += __shfl_xor(p[k], off, 64);

    if (lane == 0) {
        #pragma unroll
        for (int k = 0; k < 10; k++) Gm[(size_t)a * 12 + k] = p[k];
    }
}

// ---------------------------------------------------------------------------
// Fused cross attention (S=9): ONE WAVE per query row, 8 ch/lane per half-wave.
// Two-phase: (A) prefetch kp/mask/Gram for all samples, compute packed corner
// offsets + norm-folded weights into registers; (B) fully-unrolled K/V gather
// + blend with deep ILP. Samples interleaved across halves (5/4), combined
// via shfl_xor(...,32).
// ---------------------------------------------------------------------------
__global__ __launch_bounds__(256, 4) void cross_fused_kernel(
    const ushort_t* __restrict__ QKV, const float* __restrict__ Gm,
    const float* __restrict__ kp0, const float* __restrict__ kp1,
    const int* __restrict__ maskc0, const int* __restrict__ maskc1,
    ushort_t* __restrict__ MSG)
{
    int wv = threadIdx.x >> 6;
    int lane = threadIdx.x & 63;
    int half = lane >> 5;
    int l32 = lane & 31;
    int row = blockIdx.x * 4 + wv;

    int t = row >> 13;
    int bl = row & 8191;               // b*4096 + l
    int ts = 1 - t;                    // source image
    const float* kp = ts ? kp1 : kp0;
    const int* mask = (t == 0) ? maskc1 : maskc0;
    int img = ts * 2 + (bl >> 12);
    size_t rb = (size_t)img * 4096;    // source row base
    const float* Gimg = Gm + (size_t)img * 50700;   // 4225 * 12

    int c8 = l32 * 8;                  // this lane's 8 channels

    ushort8_t qu = *(const ushort8_t*)&QKV[(size_t)row * 768 + c8];
    float qf[8];
    #pragma unroll
    for (int j = 0; j < 8; j++) qf[j] = elu1(b2f(qu[j]));

    // ---------- phase A: prefetch + sample setup (this half's samples) ----------
    int oA[5], oB[5];
    float u0a[5], u1a[5], u2a[5], u3a[5];
    int mbits = 0;
    #pragma unroll
    for (int i = 0; i < 5; i++) {
        int s9 = 2 * i + half;
        bool valid = s9 < 9;
        int r = bl * 9 + (valid ? s9 : 0);
        bool mk = valid && (mask[r] != 0);
        if (mk) {
            float2 kxy = *(const float2*)&kp[(size_t)r * 2];
            float px = (kxy.x - 3.5f) * (63.f / 507.5f);
            float py = (kxy.y - 3.5f) * (63.f / 507.5f);
            float fx = floorf(px), fy = floorf(py);
            float wx = px - fx, wy = py - fy;
            int ix = (int)fx, iy = (int)fy;            // -1..63
            int xa = ix > 0 ? ix : 0;
            int xb = ix + 1 > 0 ? (ix + 1 < 63 ? ix + 1 : 63) : 0;
            int ya = iy > 0 ? iy : 0;
            int yb = iy + 1 > 0 ? (iy + 1 < 63 ? iy + 1 : 63) : 0;

            float w0 = (1.f - wy) * (1.f - wx);
            float w1 = (1.f - wy) * wx;
            float w2 = wy * (1.f - wx);
            float w3 = wy * wx;

            const float* G = &Gimg[(size_t)((iy + 1) * 65 + (ix + 1)) * 12];
            float4 ga = *(const float4*)&G[0];   // 00,01,02,03
            float4 gb4 = *(const float4*)&G[4];  // 11,12,13,22
            float2 gc = *(const float2*)&G[8];   // 23,33
            float ss = w0 * w0 * ga.x + w1 * w1 * gb4.x + w2 * w2 * gb4.w + w3 * w3 * gc.y
                     + 2.f * (w0 * w1 * ga.y + w0 * w2 * ga.z + w0 * w3 * ga.w
                            + w1 * w2 * gb4.y + w1 * w3 * gb4.z + w2 * w3 * gc.x);
            float inv = 1.f / (sqrtf(ss) + 1e-8f);
            u0a[i] = w0 * inv; u1a[i] = w1 * inv; u2a[i] = w2 * inv; u3a[i] = w3 * inv;
            oA[i] = (ya * 64 + xa) | ((ya * 64 + xb) << 16);
            oB[i] = (yb * 64 + xa) | ((yb * 64 + xb) << 16);
            mbits |= 1 << i;
        }
    }

    // ---------- phase B: gathers + blend ----------
    float zsum = 0.f;
    float acc[8] = {0,0,0,0,0,0,0,0};
    #pragma unroll
    for (int i = 0; i < 5; i++) {
        if ((mbits >> i) & 1) {
            size_t s00 = (rb + (oA[i] & 0xffff)) * 768;
            size_t s01 = (rb + (oA[i] >> 16)) * 768;
            size_t s10 = (rb + (oB[i] & 0xffff)) * 768;
            size_t s11 = (rb + (oB[i] >> 16)) * 768;
            float u0 = u0a[i], u1 = u1a[i], u2 = u2a[i], u3 = u3a[i];

            ushort8_t k00 = *(const ushort8_t*)&QKV[s00 + 256 + c8];
            ushort8_t k01 = *(const ushort8_t*)&QKV[s01 + 256 + c8];
            ushort8_t k10 = *(const ushort8_t*)&QKV[s10 + 256 + c8];
            ushort8_t k11 = *(const ushort8_t*)&QKV[s11 + 256 + c8];
            ushort8_t v00 = *(const ushort8_t*)&QKV[s00 + 512 + c8];
            ushort8_t v01 = *(const ushort8_t*)&QKV[s01 + 512 + c8];
            ushort8_t v10 = *(const ushort8_t*)&QKV[s10 + 512 + c8];
            ushort8_t v11 = *(const ushort8_t*)&QKV[s11 + 512 + c8];

            float vc[8];
            float p = 0.f;
            #pragma unroll
            for (int j = 0; j < 8; j++) {
                float kc = u0 * b2f(k00[j]) + u1 * b2f(k01[j])
                         + u2 * b2f(k10[j]) + u3 * b2f(k11[j]);
                vc[j] = u0 * b2f(v00[j]) + u1 * b2f(v01[j])
                      + u2 * b2f(v10[j]) + u3 * b2f(v11[j]);
                p += qf[j] * elu1(kc);
            }
            // head = 32 ch = 4 lanes (group aligned): reduce over 4 lanes
            p += __shfl_xor(p, 1, 64);
            p += __shfl_xor(p, 2, 64);

            zsum += p;
            #pragma unroll
            for (int j = 0; j < 8; j++) acc[j] += p * vc[j];
        }
    }

    // combine the two halves (same channels, disjoint samples)
    zsum += __shfl_xor(zsum, 32, 64);
    #pragma unroll
    for (int j = 0; j < 8; j++) acc[j] += __shfl_xor(acc[j], 32, 64);

    if (half == 0) {
        float Z = 1.f / (zsum + 1e-6f);
        ushort8_t o;
        #pragma unroll
        for (int j = 0; j < 8; j++) o[j] = f2b(acc[j] * Z);
        *(ushort8_t*)&MSG[(size_t)row * 256 + c8] = o;
    }
}

// ---------------------------------------------------------------------------

extern "C" void kernel_launch(void* const* d_in, const int* in_sizes, int n_in,
                              void* d_out, int out_size, void* d_ws, size_t ws_size,
                              hipStream_t stream)
{
    const float* feat0 = (const float*)d_in[0];
    const float* feat1 = (const float*)d_in[1];
    const float* kp0 = (const float*)d_in[2];
    const float* kp1 = (const float*)d_in[3];
    const int* ms0 = (const int*)d_in[4];
    const int* ms1 = (const int*)d_in[5];
    const int* mc0 = (const int*)d_in[6];
    const int* mc1 = (const int*)d_in[7];
    const float* Wq = (const float*)d_in[8];
    const float* Wk = (const float*)d_in[9];
    const float* Wv = (const float*)d_in[10];
    const float* Wm = (const float*)d_in[11];
    const float* W1 = (const float*)d_in[12];
    const float* W2 = (const float*)d_in[13];
    const float* g1 = (const float*)d_in[14];
    const float* b1 = (const float*)d_in[15];
    const float* g2 = (const float*)d_in[16];
    const float* b2 = (const float*)d_in[17];

    // workspace carve (bytes; all offsets 256B-aligned). ~55 MB total.
    char* p = (char*)d_ws;
    float*    X     = (float*)p;            p += 16777216;   // 16384x256 fp32
    ushort_t* Xbf   = (ushort_t*)p;         p += 8388608;    // bf16 mirror
    ushort_t* QKV   = (ushort_t*)p;         p += 25165824;   // 16384x768 bf16
    ushort_t* MSG   = (ushort_t*)p;         p += 8388608;    // 16384x256 bf16
    ushort_t* L1bf  = (ushort_t*)p;         p += 8388608;    // 16384x256 bf16
    float*    KVb   = (float*)p;            p += 131072;     // 32x1024
    float*    KSb   = (float*)p;            p += 4096;       // 32x32 (KVb+KSb zeroed together)
    float*    Gm    = (float*)p;            p += 811264;     // 4x4225x12 fp32 Gram (padded)
    ushort_t* Wqkvt = (ushort_t*)p;         p += 1572864;    // 4x768x256 bf16
    ushort_t* Wmt   = (ushort_t*)p;         p += 524288;     // 4x256x256
    ushort_t* W1t   = (ushort_t*)p;         p += 2097152;    // 4x512x512
    ushort_t* W2t   = (ushort_t*)p;         p += 1048576;    // 4x256x512

    init_kernel<<<4096, 256, 0, stream>>>(feat0, feat1, X, Xbf);
    wprep_kernel<<<2560, 256, 0, stream>>>(Wq, Wk, Wv, Wm, W1, W2, Wqkvt, Wmt, W1t, W2t);

    for (int i = 0; i < 4; i++) {
        const ushort_t* Wqkvt_l = Wqkvt + (size_t)i * 196608;
        const ushort_t* Wmt_l   = Wmt   + (size_t)i * 65536;
        const ushort_t* W1t_l   = W1t   + (size_t)i * 262144;
        const ushort_t* W2t_l   = W2t   + (size_t)i * 131072;
        const float* g1_l = g1 + (size_t)i * 256;
        const float* b1_l = b1 + (size_t)i * 256;
        const float* g2_l = g2 + (size_t)i * 256;
        const float* b2_l = b2 + (size_t)i * 256;
        bool is_self = (i == 0 || i == 2);

        // QKV = Xbf @ [Wq|Wk|Wv] ; self layers also zero KVb+KSb (33792 floats)
        gemm_bf16_kernel<<<dim3(6, 128), 256, 0, stream>>>(
            Xbf, 256, Wqkvt_l, 256, QKV, 768, 256,
            is_self ? KVb : nullptr, 33792 / 4);

        if (is_self) {
            kv_reduce_kernel<<<dim3(16, 32), 256, 0, stream>>>(QKV, ms0, ms1, KVb, KSb);
            attn_apply_kernel<<<NROWS, 256, 0, stream>>>(QKV, KVb, KSb, MSG);
        } else {
            gram_kernel<<<4225, 256, 0, stream>>>(Xbf, Gm);
            cross_fused_kernel<<<NROWS / 4, 256, 0, stream>>>(QKV, Gm, kp0, kp1, mc0, mc1, MSG);
        }

        // L1 = ln1(MSG @ Wm)  (fused)
        gemm_ln_kernel<<<NROWS / 32, 256, 0, stream>>>(
            MSG, 256, Wmt_l, 256, 256, g1_l, b1_l, L1bf);

        // T = tanh([Xbf|L1] @ W1) ; X += ln2(T @ W2) ; Xbf = bf16(X)  (one kernel)
        float* Xout = (i == 3) ? (float*)d_out : X;
        mlp_fused_kernel<<<NROWS / 32, 256, 0, stream>>>(
            Xbf, L1bf, W1t_l, W2t_l, g2_l, b2_l, Xbf, X, Xout);
    }
}

// Round 10
// 612.102 us; speedup vs baseline: 1.0311x; 1.0311x over previous
//
#include <hip/hip_runtime.h>
#include <cstddef>

// Shapes (hard-coded): B=2, L=4096 (64x64), C=256, H=8, D=32, K=9, scale=8,
// layers: self,cross,self,cross. X rows: 0..8191 feat0 (b0,b1), 8192..16383 feat1.

#define NROWS 16384

typedef unsigned short ushort_t;
typedef __attribute__((ext_vector_type(8))) short short8;
typedef __attribute__((ext_vector_type(4))) float f32x4;
typedef __attribute__((ext_vector_type(4))) unsigned short ushort4_t;
typedef __attribute__((ext_vector_type(8))) unsigned short ushort8_t;

__device__ __forceinline__ float b2f(unsigned short u) {
    union { unsigned int i; float f; } v; v.i = (unsigned int)u << 16; return v.f;
}
__device__ __forceinline__ unsigned short f2b(float x) {
    union { float f; unsigned int i; } v; v.f = x;
    unsigned int r = v.i + 0x7fffu + ((v.i >> 16) & 1u);   // RNE
    return (unsigned short)(r >> 16);
}
// elu(x)+1: for x<=0, elu = exp(x)-1, so elu+1 = exp(x) exactly.
__device__ __forceinline__ float elu1(float x) {
    return x > 0.f ? x + 1.f : __expf(x);
}

#define ASYNC_COPY16(gptr, lptr) \
    __builtin_amdgcn_global_load_lds((const __attribute__((address_space(1))) void*)(gptr), \
                                     (__attribute__((address_space(3))) void*)(lptr), 16, 0, 0)

// ---------------------------------------------------------------------------
// bf16 MFMA GEMM: C[M,N] = A[M,K] @ W[K,N], W pre-transposed as Wt[N][K].
// 128x128 tile, BK=64 (two 32-col LDS panels). Used for the QKV projection.
// Side duty: blocks with blockIdx.y==0 zero the KVb/KSb accumulators so the
// later kv_reduce atomics need no separate memset dispatch.
// ---------------------------------------------------------------------------
__global__ __launch_bounds__(256) void gemm_bf16_kernel(
    const ushort_t* __restrict__ A0, int lda0,
    const ushort_t* __restrict__ Wt, int ldw,
    ushort_t* __restrict__ C, int ldc, int Kd,
    float* __restrict__ zbuf, int znf4)   // zero zbuf[0..znf4*4) floats
{
    __shared__ ushort_t As[128 * 64];   // 16 KB
    __shared__ ushort_t Bs[128 * 64];   // 16 KB

    int tid = threadIdx.x;
    int m0 = blockIdx.y * 128;
    int n0 = blockIdx.x * 128;
    int lane = tid & 63, w = tid >> 6;
    int wrow = w >> 1, wcol = w & 1;
    int quad = lane >> 4, l16 = lane & 15;

    if (zbuf && blockIdx.y == 0) {
        int nblk = gridDim.x;
        for (int i = blockIdx.x * 256 + tid; i < znf4; i += nblk * 256)
            *(float4*)&zbuf[(size_t)i * 4] = (float4){0.f, 0.f, 0.f, 0.f};
    }

    f32x4 acc[4][4];
    #pragma unroll
    for (int i = 0; i < 4; i++)
        #pragma unroll
        for (int j = 0; j < 4; j++) acc[i][j] = (f32x4){0.f, 0.f, 0.f, 0.f};

    for (int kb = 0; kb < Kd; kb += 64) {
        #pragma unroll
        for (int q = 0; q < 4; q++) {
            int s = q * 256 + tid;
            int kk = s >> 9, p = s & 511;
            int row = p >> 2, c4 = p & 3;
            ASYNC_COPY16(A0 + (size_t)(m0 + row) * lda0 + kb + kk * 32 + c4 * 8,
                         (char*)As + s * 16);
        }
        #pragma unroll
        for (int q = 0; q < 4; q++) {
            int s = q * 256 + tid;
            int kk = s >> 9, p = s & 511;
            int row = p >> 2, c4 = p & 3;
            ASYNC_COPY16(Wt + (size_t)(n0 + row) * ldw + kb + kk * 32 + c4 * 8,
                         (char*)Bs + s * 16);
        }
        __syncthreads();

        #pragma unroll
        for (int kk = 0; kk < 2; kk++) {
            short8 af[4], bf[4];
            #pragma unroll
            for (int mt = 0; mt < 4; mt++)
                af[mt] = *(const short8*)&As[kk * 4096 + (wrow * 64 + mt * 16 + l16) * 32 + quad * 8];
            #pragma unroll
            for (int nt = 0; nt < 4; nt++)
                bf[nt] = *(const short8*)&Bs[kk * 4096 + (wcol * 64 + nt * 16 + l16) * 32 + quad * 8];
            #pragma unroll
            for (int mt = 0; mt < 4; mt++)
                #pragma unroll
                for (int nt = 0; nt < 4; nt++)
                    acc[mt][nt] = __builtin_amdgcn_mfma_f32_16x16x32_bf16(
                        af[mt], bf[nt], acc[mt][nt], 0, 0, 0);
        }
        __syncthreads();
    }

    #pragma unroll
    for (int mt = 0; mt < 4; mt++) {
        int row = m0 + wrow * 64 + mt * 16 + quad * 4;
        #pragma unroll
        for (int nt = 0; nt < 4; nt++) {
            int col = n0 + wcol * 64 + nt * 16 + l16;
            #pragma unroll
            for (int r = 0; r < 4; r++)
                C[(size_t)(row + r) * ldc + col] = f2b(acc[mt][nt][r]);
        }
    }
}

// ---------------------------------------------------------------------------
// GEMM + fused LayerNorm (the Wm -> ln1 path). 32 rows x 256 cols per block,
// BK=64 two-panel LDS layout. OutBf = bf16(LN(A@Wt)).
// ---------------------------------------------------------------------------
__global__ __launch_bounds__(256) void gemm_ln_kernel(
    const ushort_t* __restrict__ A, int lda,
    const ushort_t* __restrict__ Wt, int ldw, int Kd,
    const float* __restrict__ g, const float* __restrict__ bp,
    ushort_t* __restrict__ OutBf)
{
    __shared__ ushort_t As[32 * 64];    // 4 KB, panels of 32x32
    __shared__ ushort_t Bs[256 * 64];   // 32 KB, panels of 256x32
    __shared__ float rsum[4][32];
    __shared__ float rsq[4][32];

    int tid = threadIdx.x;
    int m0 = blockIdx.x * 32;
    int lane = tid & 63, w = tid >> 6;
    int quad = lane >> 4, l16 = lane & 15;

    f32x4 acc[2][4];
    #pragma unroll
    for (int i = 0; i < 2; i++)
        #pragma unroll
        for (int j = 0; j < 4; j++) acc[i][j] = (f32x4){0.f, 0.f, 0.f, 0.f};

    for (int kb = 0; kb < Kd; kb += 64) {
        {
            int s = tid;
            int kk = s >> 7, p = s & 127;
            int row = p >> 2, c4 = p & 3;
            ASYNC_COPY16(A + (size_t)(m0 + row) * lda + kb + kk * 32 + c4 * 8,
                         (char*)As + s * 16);
        }
        #pragma unroll
        for (int q = 0; q < 8; q++) {
            int s = q * 256 + tid;
            int kk = s >> 10, p = s & 1023;
            int row = p >> 2, c4 = p & 3;
            ASYNC_COPY16(Wt + (size_t)(row) * ldw + kb + kk * 32 + c4 * 8,
                         (char*)Bs + s * 16);
        }
        __syncthreads();

        #pragma unroll
        for (int kk = 0; kk < 2; kk++) {
            short8 af[2], bf[4];
            #pragma unroll
            for (int mt = 0; mt < 2; mt++)
                af[mt] = *(const short8*)&As[kk * 1024 + (mt * 16 + l16) * 32 + quad * 8];
            #pragma unroll
            for (int nt = 0; nt < 4; nt++)
                bf[nt] = *(const short8*)&Bs[kk * 8192 + (w * 64 + nt * 16 + l16) * 32 + quad * 8];
            #pragma unroll
            for (int mt = 0; mt < 2; mt++)
                #pragma unroll
                for (int nt = 0; nt < 4; nt++)
                    acc[mt][nt] = __builtin_amdgcn_mfma_f32_16x16x32_bf16(
                        af[mt], bf[nt], acc[mt][nt], 0, 0, 0);
        }
        __syncthreads();
    }

    #pragma unroll
    for (int mt = 0; mt < 2; mt++)
        #pragma unroll
        for (int r = 0; r < 4; r++) {
            float s = 0.f, q = 0.f;
            #pragma unroll
            for (int nt = 0; nt < 4; nt++) {
                float v = acc[mt][nt][r];
                s += v; q += v * v;
            }
            #pragma unroll
            for (int off = 1; off < 16; off <<= 1) {
                s += __shfl_xor(s, off, 64);
                q += __shfl_xor(q, off, 64);
            }
            if (l16 == 0) {
                rsum[w][mt * 16 + quad * 4 + r] = s;
                rsq[w][mt * 16 + quad * 4 + r]  = q;
            }
        }
    __syncthreads();

    #pragma unroll
    for (int mt = 0; mt < 2; mt++) {
        #pragma unroll
        for (int r = 0; r < 4; r++) {
            int rl = mt * 16 + quad * 4 + r;
            float s = rsum[0][rl] + rsum[1][rl] + rsum[2][rl] + rsum[3][rl];
            float q = rsq[0][rl] + rsq[1][rl] + rsq[2][rl] + rsq[3][rl];
            float m = s * (1.f / 256.f);
            float var = q * (1.f / 256.f) - m * m;
            float rs = rsqrtf(var + 1e-5f);
            size_t row = (size_t)(m0 + rl);
            #pragma unroll
            for (int nt = 0; nt < 4; nt++) {
                int col = w * 64 + nt * 16 + l16;
                float y = (acc[mt][nt][r] - m) * rs * g[col] + bp[col];
                OutBf[row * 256 + col] = f2b(y);
            }
        }
    }
}

// ---------------------------------------------------------------------------
// Fused MLP tail: per 32-row block,
//   stage1: T = tanh([Xb|L1] @ W1t)   (32x512, kept in XOR-swizzled LDS)
//   stage2: M2 = T @ W2t ; xn = Xin + LN(M2); Xout = xn; XbfOut = bf16(xn)
// ---------------------------------------------------------------------------
__global__ __launch_bounds__(256) void mlp_fused_kernel(
    const ushort_t* __restrict__ Xb, const ushort_t* __restrict__ L1,
    const ushort_t* __restrict__ W1t, const ushort_t* __restrict__ W2t,
    const float* __restrict__ g, const float* __restrict__ bp,
    ushort_t* __restrict__ XbfOut, const float* __restrict__ Xin,
    float* __restrict__ Xout)
{
    __shared__ ushort_t Tt[32 * 512];   // 32 KB, XOR-swizzled by (col>>3)^(row&7)
    __shared__ char buf[20480];         // stage1: As 4K + Bs 16K ; stage2: Bs2 16K ; epi: stats

    ushort_t* As  = (ushort_t*)buf;
    ushort_t* Bs  = (ushort_t*)(buf + 4096);
    ushort_t* Bs2 = (ushort_t*)buf;
    float* rsum = (float*)buf;          // [4][32] (dead staging region by epilogue)
    float* rsq  = (float*)(buf + 512);

    int tid = threadIdx.x;
    int m0 = blockIdx.x * 32;
    int lane = tid & 63, w = tid >> 6;
    int quad = lane >> 4, l16 = lane & 15;

    // ---------- stage 1: 4 N-passes of 128 cols ----------
    for (int np = 0; np < 4; np++) {
        f32x4 acc[2][2];
        #pragma unroll
        for (int i = 0; i < 2; i++)
            #pragma unroll
            for (int j = 0; j < 2; j++) acc[i][j] = (f32x4){0.f, 0.f, 0.f, 0.f};

        for (int kb = 0; kb < 512; kb += 64) {
            const ushort_t* Ab = (kb < 256) ? Xb : L1;
            int kc = (kb < 256) ? kb : kb - 256;
            {
                int s = tid;
                int kk = s >> 7, p = s & 127;
                ASYNC_COPY16(Ab + (size_t)(m0 + (p >> 2)) * 256 + kc + kk * 32 + (p & 3) * 8,
                             (char*)As + s * 16);
            }
            #pragma unroll
            for (int q = 0; q < 4; q++) {
                int s = q * 256 + tid;
                int kk = s >> 9, p = s & 511;
                ASYNC_COPY16(W1t + (size_t)(np * 128 + (p >> 2)) * 512 + kb + kk * 32 + (p & 3) * 8,
                             (char*)Bs + s * 16);
            }
            __syncthreads();

            #pragma unroll
            for (int kk = 0; kk < 2; kk++) {
                short8 af[2], bfr[2];
                #pragma unroll
                for (int mt = 0; mt < 2; mt++)
                    af[mt] = *(const short8*)&As[kk * 1024 + (mt * 16 + l16) * 32 + quad * 8];
                #pragma unroll
                for (int nt = 0; nt < 2; nt++)
                    bfr[nt] = *(const short8*)&Bs[kk * 4096 + (w * 32 + nt * 16 + l16) * 32 + quad * 8];
                #pragma unroll
                for (int mt = 0; mt < 2; mt++)
                    #pragma unroll
                    for (int nt = 0; nt < 2; nt++)
                        acc[mt][nt] = __builtin_amdgcn_mfma_f32_16x16x32_bf16(
                            af[mt], bfr[nt], acc[mt][nt], 0, 0, 0);
            }
            __syncthreads();
        }

        // write tanh(acc) into Tt (swizzled)
        #pragma unroll
        for (int mt = 0; mt < 2; mt++)
            #pragma unroll
            for (int nt = 0; nt < 2; nt++)
                #pragma unroll
                for (int r = 0; r < 4; r++) {
                    int trow = mt * 16 + quad * 4 + r;
                    int col = np * 128 + w * 32 + nt * 16 + l16;
                    int c8s = (col >> 3) ^ (trow & 7);
                    Tt[trow * 512 + c8s * 8 + (col & 7)] = f2b(tanhf(acc[mt][nt][r]));
                }
    }

    // ---------- stage 2: 2 N-passes of 128 cols, acc kept across passes ----------
    f32x4 acc2[2][2][2];
    #pragma unroll
    for (int a = 0; a < 2; a++)
        #pragma unroll
        for (int i = 0; i < 2; i++)
            #pragma unroll
            for (int j = 0; j < 2; j++) acc2[a][i][j] = (f32x4){0.f, 0.f, 0.f, 0.f};

    for (int pass = 0; pass < 2; pass++) {
        for (int kb = 0; kb < 512; kb += 64) {
            #pragma unroll
            for (int q = 0; q < 4; q++) {
                int s = q * 256 + tid;
                int kk = s >> 9, p = s & 511;
                ASYNC_COPY16(W2t + (size_t)(pass * 128 + (p >> 2)) * 512 + kb + kk * 32 + (p & 3) * 8,
                             (char*)Bs2 + s * 16);
            }
            __syncthreads();

            #pragma unroll
            for (int kk = 0; kk < 2; kk++) {
                short8 af[2], bfr[2];
                #pragma unroll
                for (int mt = 0; mt < 2; mt++) {
                    int row = mt * 16 + l16;
                    int blk = ((kb >> 3) + kk * 4 + quad) ^ (row & 7);
                    af[mt] = *(const short8*)&Tt[row * 512 + blk * 8];
                }
                #pragma unroll
                for (int nt = 0; nt < 2; nt++)
                    bfr[nt] = *(const short8*)&Bs2[kk * 4096 + (w * 32 + nt * 16 + l16) * 32 + quad * 8];
                #pragma unroll
                for (int mt = 0; mt < 2; mt++)
                    #pragma unroll
                    for (int nt = 0; nt < 2; nt++)
                        acc2[pass][mt][nt] = __builtin_amdgcn_mfma_f32_16x16x32_bf16(
                            af[mt], bfr[nt], acc2[pass][mt][nt], 0, 0, 0);
            }
            __syncthreads();
        }
    }

    // ---------- epilogue: LN + residual ----------
    #pragma unroll
    for (int mt = 0; mt < 2; mt++)
        #pragma unroll
        for (int r = 0; r < 4; r++) {
            float s = 0.f, q = 0.f;
            #pragma unroll
            for (int pass = 0; pass < 2; pass++)
                #pragma unroll
                for (int nt = 0; nt < 2; nt++) {
                    float v = acc2[pass][mt][nt][r];
                    s += v; q += v * v;
                }
            #pragma unroll
            for (int off = 1; off < 16; off <<= 1) {
                s += __shfl_xor(s, off, 64);
                q += __shfl_xor(q, off, 64);
            }
            if (l16 == 0) {
                rsum[w * 32 + mt * 16 + quad * 4 + r] = s;
                rsq[w * 32 + mt * 16 + quad * 4 + r]  = q;
            }
        }
    __syncthreads();

    #pragma unroll
    for (int mt = 0; mt < 2; mt++) {
        #pragma unroll
        for (int r = 0; r < 4; r++) {
            int rl = mt * 16 + quad * 4 + r;
            float s = rsum[rl] + rsum[32 + rl] + rsum[64 + rl] + rsum[96 + rl];
            float q = rsq[rl] + rsq[32 + rl] + rsq[64 + rl] + rsq[96 + rl];
            float m = s * (1.f / 256.f);
            float var = q * (1.f / 256.f) - m * m;
            float rs = rsqrtf(var + 1e-5f);
            size_t row = (size_t)(m0 + rl);
            #pragma unroll
            for (int pass = 0; pass < 2; pass++)
                #pragma unroll
                for (int nt = 0; nt < 2; nt++) {
                    int col = pass * 128 + w * 32 + nt * 16 + l16;
                    float y = (acc2[pass][mt][nt][r] - m) * rs * g[col] + bp[col];
                    float xn = Xin[row * 256 + col] + y;
                    Xout[row * 256 + col] = xn;
                    XbfOut[row * 256 + col] = f2b(xn);
                }
        }
    }
}

// ---------------------------------------------------------------------------
// Weight prep: fp32 [K][N] -> bf16 transposed [N][K]; q/k/v fused into [768][256].
// ---------------------------------------------------------------------------
__global__ __launch_bounds__(256) void wprep_kernel(
    const float* __restrict__ Wq, const float* __restrict__ Wk,
    const float* __restrict__ Wv, const float* __restrict__ Wm,
    const float* __restrict__ W1, const float* __restrict__ W2,
    ushort_t* __restrict__ Wqkvt, ushort_t* __restrict__ Wmt,
    ushort_t* __restrict__ W1t, ushort_t* __restrict__ W2t)
{
    int t = blockIdx.x;
    int layer = t / 640, r = t % 640;
    const float* src; ushort_t* dst;
    int ldsrc, lddst, tn, tk;
    if (r < 192) {
        int grp = r / 64, rr = r % 64; tn = rr / 8; tk = rr % 8;
        src = (grp == 0 ? Wq : grp == 1 ? Wk : Wv) + (size_t)layer * 65536;
        ldsrc = 256;
        dst = Wqkvt + (size_t)layer * 196608 + (size_t)grp * 65536;
        lddst = 256;
    } else if (r < 256) {
        int rr = r - 192; tn = rr / 8; tk = rr % 8;
        src = Wm + (size_t)layer * 65536; ldsrc = 256;
        dst = Wmt + (size_t)layer * 65536; lddst = 256;
    } else if (r < 512) {
        int rr = r - 256; tn = rr / 16; tk = rr % 16;
        src = W1 + (size_t)layer * 262144; ldsrc = 512;
        dst = W1t + (size_t)layer * 262144; lddst = 512;
    } else {
        int rr = r - 512; tn = rr / 16; tk = rr % 16;
        src = W2 + (size_t)layer * 131072; ldsrc = 256;
        dst = W2t + (size_t)layer * 131072; lddst = 512;
    }
    int n0 = tn * 32, k0 = tk * 32;
    __shared__ float tileS[32][33];
    int j = threadIdx.x & 31, i0 = threadIdx.x >> 5;
    #pragma unroll
    for (int p = 0; p < 4; p++) {
        int i = i0 + p * 8;
        tileS[i][j] = src[(size_t)(k0 + i) * ldsrc + n0 + j];
    }
    __syncthreads();
    #pragma unroll
    for (int p = 0; p < 4; p++) {
        int i = i0 + p * 8;
        dst[(size_t)(n0 + i) * lddst + k0 + j] = f2b(tileS[j][i]);
    }
}

// init: X fp32 master + Xbf bf16 mirror from feat0/feat1
__global__ __launch_bounds__(256) void init_kernel(
    const float* __restrict__ f0, const float* __restrict__ f1,
    float* __restrict__ X, ushort_t* __restrict__ Xbf)
{
    int idx = blockIdx.x * 256 + threadIdx.x;      // per float4; 1,048,576 total
    size_t e = (size_t)idx * 4;
    float4 v = (e < 2097152) ? *(const float4*)&f0[e] : *(const float4*)&f1[e - 2097152];
    *(float4*)&X[e] = v;
    ushort4_t u = { f2b(v.x), f2b(v.y), f2b(v.z), f2b(v.w) };
    *(ushort4_t*)&Xbf[e] = u;
}

// ---------------------------------------------------------------------------
// Self-attention KV[g,32,32] + Ksum[g,32] over S=4096, bf16 in (QKV fused, ld=768).
// ---------------------------------------------------------------------------
__global__ __launch_bounds__(256) void kv_reduce_kernel(
    const ushort_t* __restrict__ QKV,
    const int* __restrict__ mask0, const int* __restrict__ mask1,
    float* __restrict__ KV, float* __restrict__ Ksum)
{
    int g = blockIdx.y;
    int t = g >> 4, b = (g >> 3) & 1, h = g & 7;
    const int* mask = t ? mask1 : mask0;
    int rowbase = t * 8192 + b * 4096;
    int s_begin = blockIdx.x * 256;

    __shared__ float sK[32][32];
    __shared__ float sV[32][32];

    int tid = threadIdx.x;
    int e  = tid & 31;
    int dq = tid >> 5;              // 0..7 ; this thread owns d = dq*4..dq*4+3

    float acc[4] = {0.f, 0.f, 0.f, 0.f};
    float ks[4]  = {0.f, 0.f, 0.f, 0.f};

    for (int s0 = s_begin; s0 < s_begin + 256; s0 += 32) {
        #pragma unroll
        for (int q = 0; q < 2; q++) {
            int idx = tid + q * 256;
            int rl = idx >> 4;
            int part = idx & 15;
            int s = s0 + rl;
            size_t row = (size_t)(rowbase + s);
            float m = mask[b * 4096 + s] ? 1.f : 0.f;
            if (part < 8) {
                ushort4_t u = *(const ushort4_t*)&QKV[row * 768 + 256 + h * 32 + part * 4];
                float4 f = { elu1(b2f(u.x)) * m, elu1(b2f(u.y)) * m,
                             elu1(b2f(u.z)) * m, elu1(b2f(u.w)) * m };
                *(float4*)&sK[rl][part * 4] = f;
            } else {
                ushort4_t u = *(const ushort4_t*)&QKV[row * 768 + 512 + h * 32 + (part - 8) * 4];
                float4 f = { b2f(u.x) * m, b2f(u.y) * m, b2f(u.z) * m, b2f(u.w) * m };
                *(float4*)&sV[rl][(part - 8) * 4] = f;
            }
        }
        __syncthreads();

        #pragma unroll
        for (int s = 0; s < 32; s++) {
            float4 kq = *(const float4*)&sK[s][dq * 4];
            float vv = sV[s][e];
            acc[0] += kq.x * vv;
            acc[1] += kq.y * vv;
            acc[2] += kq.z * vv;
            acc[3] += kq.w * vv;
            ks[0] += kq.x; ks[1] += kq.y; ks[2] += kq.z; ks[3] += kq.w;
        }
        __syncthreads();
    }

    #pragma unroll
    for (int j = 0; j < 4; j++)
        atomicAdd(&KV[(size_t)g * 1024 + (dq * 4 + j) * 32 + e], acc[j]);
    if (e == 0) {
        #pragma unroll
        for (int j = 0; j < 4; j++)
            atomicAdd(&Ksum[g * 32 + dq * 4 + j], ks[j]);
    }
}

__global__ __launch_bounds__(256) void attn_apply_kernel(
    const ushort_t* __restrict__ QKV, const float* __restrict__ KV,
    const float* __restrict__ Ksum, ushort_t* __restrict__ MSG)
{
    int row = blockIdx.x;
    int t = row >> 13, bb = (row >> 12) & 1;
    int gb = (t * 2 + bb) * 8;
    int c = threadIdx.x, h = c >> 5, e = c & 31;
    int g = gb + h;

    __shared__ float sQ[256];
    float qf = elu1(b2f(QKV[(size_t)row * 768 + c]));
    sQ[c] = qf;
    __syncthreads();

    float p = qf * Ksum[g * 32 + e];
    #pragma unroll
    for (int off = 16; off; off >>= 1) p += __shfl_xor(p, off, 32);
    float Z = 1.f / (p + 1e-6f);

    float acc = 0.f;
    #pragma unroll
    for (int d = 0; d < 32; d++)
        acc += sQ[h * 32 + d] * KV[(size_t)g * 1024 + d * 32 + e];

    MSG[(size_t)row * 256 + c] = f2b(acc * Z);
}

// ---------------------------------------------------------------------------
// Gram table: 12-float stride (10 used + 2 pad for 16B-aligned loads).
// G order: 00,01,02,03,11,12,13,22,23,33.
// ---------------------------------------------------------------------------
__global__ __launch_bounds__(256) void gram_kernel(
    const ushort_t* __restrict__ Xbf, float* __restrict__ Gm)
{
    int a = blockIdx.x * 4 + (threadIdx.x >> 6);
    int lane = threadIdx.x & 63;
    int img = a / 4225;
    int rr = a - img * 4225;
    int ay = rr / 65, ax = rr - ay * 65;
    int xa = ax > 0 ? ax - 1 : 0;
    int xb = ax < 64 ? ax : 63;
    if (ax == 0) xb = 0;
    int ya = ay > 0 ? ay - 1 : 0;
    int yb = ay < 64 ? ay : 63;
    if (ay == 0) yb = 0;

    size_t rbase = (size_t)img * 4096;
    size_t r0 = (rbase + ya * 64 + xa) * 256;
    size_t r1 = (rbase + ya * 64 + xb) * 256;
    size_t r2 = (rbase + yb * 64 + xa) * 256;
    size_t r3 = (rbase + yb * 64 + xb) * 256;

    int c4 = lane * 4;
    ushort4_t u0 = *(const ushort4_t*)&Xbf[r0 + c4];
    ushort4_t u1 = *(const ushort4_t*)&Xbf[r1 + c4];
    ushort4_t u2 = *(const ushort4_t*)&Xbf[r2 + c4];
    ushort4_t u3 = *(const ushort4_t*)&Xbf[r3 + c4];

    float p[10] = {0,0,0,0,0,0,0,0,0,0};
    #pragma unroll
    for (int j = 0; j < 4; j++) {
        float f0 = b2f(u0[j]), f1 = b2f(u1[j]), f2 = b2f(u2[j]), f3 = b2f(u3[j]);
        p[0] += f0 * f0; p[1] += f0 * f1; p[2] += f0 * f2; p[3] += f0 * f3;
        p[4] += f1 * f1; p[5] += f1 * f2; p[6] += f1 * f3;
        p[7] += f2 * f2; p[8] += f2 * f3; p[9] += f3 * f3;
    }
    #pragma unroll
    for (int k = 0; k < 10; k++)
        #pragma unroll
        for (int off = 32; off; off >>= 1) p[k] += __shfl_xor(p[k], off, 64);

    if (lane == 0) {
        #pragma unroll
        for (int k = 0; k < 10; k++) Gm[(size_t)a * 12 + k] = p[k];
    }
}

// ---------------------------------------------------------------------------
// Fused cross attention (S=9): ONE WAVE per query row, 8 ch/lane per half-wave
// (both halves cover all 256 ch). Samples interleaved across halves (5/4),
// combined at the end via shfl_xor(...,32). Mask-skip per sample.
// XCD-aware swizzle: blockIdx%8 ~ XCD; map so each XCD-pair works one (t,b)
// quadrant -> per-XCD source K/V working set drops 24 MB -> 6 MB (L2 locality).
// ---------------------------------------------------------------------------
__global__ __launch_bounds__(256) void cross_fused_kernel(
    const ushort_t* __restrict__ QKV, const float* __restrict__ Gm,
    const float* __restrict__ kp0, const float* __restrict__ kp1,
    const int* __restrict__ maskc0, const int* __restrict__ maskc1,
    ushort_t* __restrict__ MSG)
{
    int wv = threadIdx.x >> 6;
    int lane = threadIdx.x & 63;
    int half = lane >> 5;
    int l32 = lane & 31;

    // quadrant swizzle: qd = (blk&7)>>1, within-quadrant = (blk>>3)*2 + (blk&1)
    int blk = blockIdx.x;
    int qd = (blk & 7) >> 1;
    int within = ((blk >> 3) << 1) | (blk & 1);    // 0..1023
    int row = qd * 4096 + within * 4 + wv;

    int t = row >> 13;
    int bl = row & 8191;               // b*4096 + l
    int ts = 1 - t;                    // source image
    const float* kp = ts ? kp1 : kp0;
    const int* mask = (t == 0) ? maskc1 : maskc0;
    int img = ts * 2 + (bl >> 12);
    size_t rb = (size_t)img * 4096;    // source row base
    const float* Gimg = Gm + (size_t)img * 50700;   // 4225 * 12

    int c8 = l32 * 8;                  // this lane's 8 channels

    ushort8_t qu = *(const ushort8_t*)&QKV[(size_t)row * 768 + c8];
    float qf[8];
    #pragma unroll
    for (int j = 0; j < 8; j++) qf[j] = elu1(b2f(qu[j]));

    float zsum = 0.f;
    float acc[8] = {0,0,0,0,0,0,0,0};

    for (int s9 = half; s9 < 9; s9 += 2) {
        int r = bl * 9 + s9;
        bool mk = mask[r] != 0;
        if (mk) {
            float xx = kp[(size_t)r * 2 + 0];
            float yy = kp[(size_t)r * 2 + 1];
            float px = (xx - 3.5f) * (63.f / 507.5f);
            float py = (yy - 3.5f) * (63.f / 507.5f);
            float fx = floorf(px), fy = floorf(py);
            float wx = px - fx, wy = py - fy;
            int ix = (int)fx, iy = (int)fy;            // -1..63
            int xa = ix > 0 ? ix : 0;
            int xb = ix + 1 > 0 ? (ix + 1 < 63 ? ix + 1 : 63) : 0;
            int ya = iy > 0 ? iy : 0;
            int yb = iy + 1 > 0 ? (iy + 1 < 63 ? iy + 1 : 63) : 0;

            float w0 = (1.f - wy) * (1.f - wx);
            float w1 = (1.f - wy) * wx;
            float w2 = wy * (1.f - wx);
            float w3 = wy * wx;

            const float* G = &Gimg[(size_t)((iy + 1) * 65 + (ix + 1)) * 12];
            float4 ga = *(const float4*)&G[0];   // 00,01,02,03
            float4 gb4 = *(const float4*)&G[4];  // 11,12,13,22
            float2 gc = *(const float2*)&G[8];   // 23,33
            float ss = w0 * w0 * ga.x + w1 * w1 * gb4.x + w2 * w2 * gb4.w + w3 * w3 * gc.y
                     + 2.f * (w0 * w1 * ga.y + w0 * w2 * ga.z + w0 * w3 * ga.w
                            + w1 * w2 * gb4.y + w1 * w3 * gb4.z + w2 * w3 * gc.x);
            float inv = 1.f / (sqrtf(ss) + 1e-8f);
            float u0 = w0 * inv, u1 = w1 * inv, u2 = w2 * inv, u3 = w3 * inv;

            size_t s00 = (rb + ya * 64 + xa) * 768;
            size_t s01 = (rb + ya * 64 + xb) * 768;
            size_t s10 = (rb + yb * 64 + xa) * 768;
            size_t s11 = (rb + yb * 64 + xb) * 768;

            ushort8_t k00 = *(const ushort8_t*)&QKV[s00 + 256 + c8];
            ushort8_t k01 = *(const ushort8_t*)&QKV[s01 + 256 + c8];
            ushort8_t k10 = *(const ushort8_t*)&QKV[s10 + 256 + c8];
            ushort8_t k11 = *(const ushort8_t*)&QKV[s11 + 256 + c8];
            ushort8_t v00 = *(const ushort8_t*)&QKV[s00 + 512 + c8];
            ushort8_t v01 = *(const ushort8_t*)&QKV[s01 + 512 + c8];
            ushort8_t v10 = *(const ushort8_t*)&QKV[s10 + 512 + c8];
            ushort8_t v11 = *(const ushort8_t*)&QKV[s11 + 512 + c8];

            float vc[8];
            float p = 0.f;
            #pragma unroll
            for (int j = 0; j < 8; j++) {
                float kc = u0 * b2f(k00[j]) + u1 * b2f(k01[j])
                         + u2 * b2f(k10[j]) + u3 * b2f(k11[j]);
                vc[j] = u0 * b2f(v00[j]) + u1 * b2f(v01[j])
                      + u2 * b2f(v10[j]) + u3 * b2f(v11[j]);
                p += qf[j] * elu1(kc);
            }
            // head = 32 ch = 4 lanes (group aligned): reduce over 4 lanes
            p += __shfl_xor(p, 1, 64);
            p += __shfl_xor(p, 2, 64);

            zsum += p;
            #pragma unroll
            for (int j = 0; j < 8; j++) acc[j] += p * vc[j];
        }
    }

    // combine the two halves (same channels, disjoint samples)
    zsum += __shfl_xor(zsum, 32, 64);
    #pragma unroll
    for (int j = 0; j < 8; j++) acc[j] += __shfl_xor(acc[j], 32, 64);

    if (half == 0) {
        float Z = 1.f / (zsum + 1e-6f);
        ushort8_t o;
        #pragma unroll
        for (int j = 0; j < 8; j++) o[j] = f2b(acc[j] * Z);
        *(ushort8_t*)&MSG[(size_t)row * 256 + c8] = o;
    }
}

// ---------------------------------------------------------------------------

extern "C" void kernel_launch(void* const* d_in, const int* in_sizes, int n_in,
                              void* d_out, int out_size, void* d_ws, size_t ws_size,
                              hipStream_t stream)
{
    const float* feat0 = (const float*)d_in[0];
    const float* feat1 = (const float*)d_in[1];
    const float* kp0 = (const float*)d_in[2];
    const float* kp1 = (const float*)d_in[3];
    const int* ms0 = (const int*)d_in[4];
    const int* ms1 = (const int*)d_in[5];
    const int* mc0 = (const int*)d_in[6];
    const int* mc1 = (const int*)d_in[7];
    const float* Wq = (const float*)d_in[8];
    const float* Wk = (const float*)d_in[9];
    const float* Wv = (const float*)d_in[10];
    const float* Wm = (const float*)d_in[11];
    const float* W1 = (const float*)d_in[12];
    const float* W2 = (const float*)d_in[13];
    const float* g1 = (const float*)d_in[14];
    const float* b1 = (const float*)d_in[15];
    const float* g2 = (const float*)d_in[16];
    const float* b2 = (const float*)d_in[17];

    // workspace carve (bytes; all offsets 256B-aligned). ~55 MB total.
    char* p = (char*)d_ws;
    float*    X     = (float*)p;            p += 16777216;   // 16384x256 fp32
    ushort_t* Xbf   = (ushort_t*)p;         p += 8388608;    // bf16 mirror
    ushort_t* QKV   = (ushort_t*)p;         p += 25165824;   // 16384x768 bf16
    ushort_t* MSG   = (ushort_t*)p;         p += 8388608;    // 16384x256 bf16
    ushort_t* L1bf  = (ushort_t*)p;         p += 8388608;    // 16384x256 bf16
    float*    KVb   = (float*)p;            p += 131072;     // 32x1024
    float*    KSb   = (float*)p;            p += 4096;       // 32x32 (KVb+KSb zeroed together)
    float*    Gm    = (float*)p;            p += 811264;     // 4x4225x12 fp32 Gram (padded)
    ushort_t* Wqkvt = (ushort_t*)p;         p += 1572864;    // 4x768x256 bf16
    ushort_t* Wmt   = (ushort_t*)p;         p += 524288;     // 4x256x256
    ushort_t* W1t   = (ushort_t*)p;         p += 2097152;    // 4x512x512
    ushort_t* W2t   = (ushort_t*)p;         p += 1048576;    // 4x256x512

    init_kernel<<<4096, 256, 0, stream>>>(feat0, feat1, X, Xbf);
    wprep_kernel<<<2560, 256, 0, stream>>>(Wq, Wk, Wv, Wm, W1, W2, Wqkvt, Wmt, W1t, W2t);

    for (int i = 0; i < 4; i++) {
        const ushort_t* Wqkvt_l = Wqkvt + (size_t)i * 196608;
        const ushort_t* Wmt_l   = Wmt   + (size_t)i * 65536;
        const ushort_t* W1t_l   = W1t   + (size_t)i * 262144;
        const ushort_t* W2t_l   = W2t   + (size_t)i * 131072;
        const float* g1_l = g1 + (size_t)i * 256;
        const float* b1_l = b1 + (size_t)i * 256;
        const float* g2_l = g2 + (size_t)i * 256;
        const float* b2_l = b2 + (size_t)i * 256;
        bool is_self = (i == 0 || i == 2);

        // QKV = Xbf @ [Wq|Wk|Wv] ; self layers also zero KVb+KSb (33792 floats)
        gemm_bf16_kernel<<<dim3(6, 128), 256, 0, stream>>>(
            Xbf, 256, Wqkvt_l, 256, QKV, 768, 256,
            is_self ? KVb : nullptr, 33792 / 4);

        if (is_self) {
            kv_reduce_kernel<<<dim3(16, 32), 256, 0, stream>>>(QKV, ms0, ms1, KVb, KSb);
            attn_apply_kernel<<<NROWS, 256, 0, stream>>>(QKV, KVb, KSb, MSG);
        } else {
            gram_kernel<<<4225, 256, 0, stream>>>(Xbf, Gm);
            cross_fused_kernel<<<NROWS / 4, 256, 0, stream>>>(QKV, Gm, kp0, kp1, mc0, mc1, MSG);
        }

        // L1 = ln1(MSG @ Wm)  (fused)
        gemm_ln_kernel<<<NROWS / 32, 256, 0, stream>>>(
            MSG, 256, Wmt_l, 256, 256, g1_l, b1_l, L1bf);

        // T = tanh([Xbf|L1] @ W1) ; X += ln2(T @ W2) ; Xbf = bf16(X)  (one kernel)
        float* Xout = (i == 3) ? (float*)d_out : X;
        mlp_fused_kernel<<<NROWS / 32, 256, 0, stream>>>(
            Xbf, L1bf, W1t_l, W2t_l, g2_l, b2_l, Xbf, X, Xout);
    }
}